// Round 1
// 4113.084 us; speedup vs baseline: 1.1525x; 1.1525x over previous
//
#include <hip/hip_runtime.h>

// Problem constants (B,S,D,H = 64,512,1024,1024)
#define S_LEN 512
#define BATCH 64
#define HDIM  1024
#define GDIM  3072   // 3*H

typedef __attribute__((ext_vector_type(8))) short bf16x8;           // MFMA A/B frag (8 bf16)
typedef __attribute__((ext_vector_type(4))) float f32x4;            // MFMA C/D frag
typedef __attribute__((ext_vector_type(4))) unsigned short u16x4;   // 4 bf16

__device__ inline unsigned short f2bf(float f) {
  unsigned u = __builtin_bit_cast(unsigned, f);
  u += 0x7fffu + ((u >> 16) & 1u);          // RNE (inputs are normal floats)
  return (unsigned short)(u >> 16);
}
__device__ inline float bf2f(unsigned short h) {
  unsigned u = ((unsigned)h) << 16;
  return __builtin_bit_cast(float, u);
}
__device__ inline bf16x8 pack8(float4 a, float4 b) {
  bf16x8 r;
  r[0] = (short)f2bf(a.x); r[1] = (short)f2bf(a.y);
  r[2] = (short)f2bf(a.z); r[3] = (short)f2bf(a.w);
  r[4] = (short)f2bf(b.x); r[5] = (short)f2bf(b.y);
  r[6] = (short)f2bf(b.z); r[7] = (short)f2bf(b.w);
  return r;
}

// ---------------------------------------------------------------------------
// Phase 1: xg[s][g][b] = sum_d U[b][s][d] * Wih[g][d] + bih[g]   (bf16 out)
// (unchanged this round)
// ---------------------------------------------------------------------------
__global__ __launch_bounds__(256, 2) void xg_gemm(
    const float* __restrict__ U, const float* __restrict__ Wih,
    const float* __restrict__ bih, unsigned short* __restrict__ xg) {
  __shared__ bf16x8 Asub[512];   // 128 rows x 4 chunks (8KB)
  __shared__ bf16x8 Bsub[512];

  const int bid = blockIdx.x;
  const int nt = bid % 24;       // N-tile (gate cols) fastest: W_ih L2 reuse
  const int mt = bid / 24;
  const int tid = threadIdx.x;
  const int wave = tid >> 6, lane = tid & 63;
  const int q = lane >> 4, l15 = lane & 15;
  const int wm = wave >> 1, wn = wave & 1;

  const int srow = tid >> 1, shalf = tid & 1;
  const int arow = mt * 128 + srow;            // M index = s*64+b ordering
  const float* Ag = U + ((size_t)(arow & 63) * S_LEN + (arow >> 6)) * HDIM + shalf * 16;
  const float* Bg = Wih + (size_t)(nt * 128 + srow) * HDIM + shalf * 16;
  const int sw = (srow >> 1) & 3;
  const int slot0 = srow * 4 + ((shalf * 2) ^ sw);
  const int slot1 = srow * 4 + ((shalf * 2 + 1) ^ sw);

  f32x4 acc[4][4];
#pragma unroll
  for (int i = 0; i < 4; ++i)
#pragma unroll
    for (int j = 0; j < 4; ++j) acc[i][j] = (f32x4){0.f, 0.f, 0.f, 0.f};

  for (int kk = 0; kk < 32; ++kk) {
    const float4* ap = (const float4*)(Ag + kk * 32);
    float4 a0 = ap[0], a1 = ap[1], a2 = ap[2], a3 = ap[3];
    const float4* bp = (const float4*)(Bg + kk * 32);
    float4 b0 = bp[0], b1 = bp[1], b2 = bp[2], b3 = bp[3];
    Asub[slot0] = pack8(a0, a1);
    Asub[slot1] = pack8(a2, a3);
    Bsub[slot0] = pack8(b0, b1);
    Bsub[slot1] = pack8(b2, b3);
    __syncthreads();
    bf16x8 af[4], bfr[4];
#pragma unroll
    for (int i = 0; i < 4; ++i) {
      int ar = wm * 64 + i * 16 + l15;
      af[i] = Asub[ar * 4 + (q ^ ((ar >> 1) & 3))];
      int br = wn * 64 + i * 16 + l15;
      bfr[i] = Bsub[br * 4 + (q ^ ((br >> 1) & 3))];
    }
#pragma unroll
    for (int i = 0; i < 4; ++i)
#pragma unroll
      for (int j = 0; j < 4; ++j)
        acc[i][j] = __builtin_amdgcn_mfma_f32_16x16x32_bf16(af[i], bfr[j], acc[i][j], 0, 0, 0);
    __syncthreads();
  }

#pragma unroll
  for (int j = 0; j < 4; ++j) {
    int gcol = nt * 128 + wn * 64 + j * 16 + l15;
    float bias = bih[gcol];
#pragma unroll
    for (int i = 0; i < 4; ++i) {
      int rbase = mt * 128 + wm * 64 + i * 16 + q * 4;
      int s = rbase >> 6;
      int b0i = rbase & 63;
      u16x4 pk;
#pragma unroll
      for (int r = 0; r < 4; ++r) pk[r] = f2bf(acc[i][j][r] + bias);
      *(u16x4*)(xg + ((size_t)s * GDIM + gcol) * BATCH + b0i) = pk;
    }
  }
}

// ---------------------------------------------------------------------------
// Phase 2 (round-6): persistent GRU scan, 64 blocks x 256 threads.
//
// Round-6 change: the per-step h read was 8 serialized L2-miss rounds (the
// inner kk loop only had 4 loads in flight; after the acquire buffer_inv every
// round was a fresh ~0.85us MALL RT -> ~5-6us/step of pure load stall,
// matching MfmaUtil=2%). Now each wave DMA-stages its whole 32KB h-slice
// h[0:64][k0:k0+256) with 32 concurrent global_load_lds (width=16) -> one
// overlapped RT instead of 8. MFMA operands come from LDS via ds_read_b128.
//
// LDS layout: h_stage[4][64*256] bf16 (128KB), wave-private regions.
//   Swizzle (bank-conflict-free reads): within region, row b's 16B chunk c is
//   stored at chunk slot c ^ (b&7). global_load_lds writes LDS linearly
//   (base + lane*16), so the swizzle is applied by pre-swizzling the GLOBAL
//   source address per lane (G21/m173 pattern). Read slot distribution per
//   ds_read_b128: 8 lanes per 16B bank-slot = the b128 conflict-free floor.
//   After the MFMA phase, wave w's partial-gate buffer (3*16*66 floats =
//   12.7KB) aliases the front of its own region: every partial store
//   data-depends on all of this wave's ds_reads, plus sched_barrier(0) and an
//   opaque-pointer asm to forbid TBAA reordering.
//
// Sync protocol (unchanged from round-5):
//  * h stores: 8B relaxed agent atomics (write-through to MALL) -> no wbl2.
//  * barrier: flag array; block p stores t+1 to flags[p]; wave 0 polls.
//  * one acquire agent fence (buffer_inv sc1) -> cached h reads fresh, L2
//    fills shared by the 8 blocks/XCD.
//  * xg prefetch for t+1 issued between flag store and poll.
// ---------------------------------------------------------------------------
__global__ __launch_bounds__(256, 1) void gru_scan(
    const float* __restrict__ Whh, const float* __restrict__ bhh,
    const unsigned short* __restrict__ xg, unsigned short* __restrict__ hbuf,
    unsigned int* __restrict__ flags, float* __restrict__ out) {
  __shared__ unsigned short h_stage[4][64 * 256];  // 128KB: staged h + aliased partials
  __shared__ float hown[64][16];                   // fp32 carry [b][m]
  __shared__ float bh_lds[3][16];

  const int p = blockIdx.x;
  const int j0 = p * 16;
  const int tid = threadIdx.x;
  const int w = tid >> 6, lane = tid & 63;
  const int q = lane >> 4, l15 = lane & 15;
  const int k0 = w * 256;
  const int cb = tid >> 2;            // combine: batch row 0..63
  const int cmq = (tid & 3) * 4;      // combine: m-quad 0,4,8,12

  // staging lane decomposition: issue i covers rows {2i, 2i+1}, 32 chunks each
  const int i2 = lane >> 5;           // which of the 2 rows this lane fills
  const int cpos = lane & 31;         // 16B chunk slot within the row

  // A-frags: wf[g][kk] = Whh[g*1024 + j0 + l15][k0 + kk*32 + q*8 .. +7]
  bf16x8 wf[3][8];
#pragma unroll
  for (int g = 0; g < 3; ++g) {
    const float* wrow = Whh + ((size_t)g * HDIM + j0 + l15) * HDIM + k0;
#pragma unroll
    for (int kk = 0; kk < 8; ++kk) {
      const float4* wp = (const float4*)(wrow + kk * 32 + q * 8);
      wf[g][kk] = pack8(wp[0], wp[1]);
    }
  }
  if (tid < 48) bh_lds[tid >> 4][tid & 15] = bhh[(tid >> 4) * HDIM + j0 + (tid & 15)];
  { float4 z = {0.f, 0.f, 0.f, 0.f}; *(float4*)&hown[cb][cmq] = z; }
  __syncthreads();

  // prefetch xg for t=0
  unsigned short xq[3][4];
#pragma unroll
  for (int g = 0; g < 3; ++g)
#pragma unroll
    for (int r = 0; r < 4; ++r)
      xq[g][r] = xg[((size_t)g * HDIM + j0 + cmq + r) * BATCH + cb];

  for (int t = 0; t < S_LEN; ++t) {
    const unsigned short* hcur = hbuf + (size_t)(t & 1) * (BATCH * HDIM);
    unsigned short* hnxt = hbuf + (size_t)((t + 1) & 1) * (BATCH * HDIM);

    // ---- stage h[0:64][k0:k0+256) into LDS: 32 async DMA issues, all in
    //      flight concurrently (this is the round-6 latency fix) ----
    {
      const unsigned short* hsrc = hcur + k0;
#pragma unroll
      for (int i = 0; i < 32; ++i) {
        const int b = 2 * i + i2;
        const int gch = cpos ^ (b & 7);                 // inverse swizzle on SOURCE
        const unsigned short* g = hsrc + (size_t)b * HDIM + gch * 8;
        __builtin_amdgcn_global_load_lds(
            (const __attribute__((address_space(1))) void*)g,
            (__attribute__((address_space(3))) void*)(&h_stage[w][i * 512]),
            16, 0, 0);
      }
    }
    asm volatile("s_waitcnt vmcnt(0)" ::: "memory");
    __builtin_amdgcn_sched_barrier(0);

    // ---- GEMM phase: hgT partials from LDS (conflict-free swizzled reads) ----
    f32x4 acc[3][4];
#pragma unroll
    for (int g = 0; g < 3; ++g)
#pragma unroll
      for (int bt = 0; bt < 4; ++bt) acc[g][bt] = (f32x4){0.f, 0.f, 0.f, 0.f};

    const unsigned short* hl = h_stage[w];
#pragma unroll
    for (int kk = 0; kk < 8; ++kk) {
      const int csw = (((kk * 4 + q) ^ (l15 & 7)) * 8);  // swizzled chunk, ushort units
      bf16x8 h0 = *(const bf16x8*)(hl + (l15)      * 256 + csw);
      bf16x8 h1 = *(const bf16x8*)(hl + (16 + l15) * 256 + csw);
      bf16x8 h2 = *(const bf16x8*)(hl + (32 + l15) * 256 + csw);
      bf16x8 h3 = *(const bf16x8*)(hl + (48 + l15) * 256 + csw);
#pragma unroll
      for (int g = 0; g < 3; ++g) {
        acc[g][0] = __builtin_amdgcn_mfma_f32_16x16x32_bf16(wf[g][kk], h0, acc[g][0], 0, 0, 0);
        acc[g][1] = __builtin_amdgcn_mfma_f32_16x16x32_bf16(wf[g][kk], h1, acc[g][1], 0, 0, 0);
        acc[g][2] = __builtin_amdgcn_mfma_f32_16x16x32_bf16(wf[g][kk], h2, acc[g][2], 0, 0, 0);
        acc[g][3] = __builtin_amdgcn_mfma_f32_16x16x32_bf16(wf[g][kk], h3, acc[g][3], 0, 0, 0);
      }
    }
    __builtin_amdgcn_sched_barrier(0);

    // partials aliased into wave w's own stage region (reads all consumed):
    // part[w] layout: float[(g*16 + m)*66 + b], m = q*4+r, b = bt*16+l15
    {
      float* pw = (float*)(void*)h_stage[w];
      asm volatile("" : "+v"(pw));   // opaque: may alias anything
#pragma unroll
      for (int g = 0; g < 3; ++g)
#pragma unroll
        for (int bt = 0; bt < 4; ++bt)
#pragma unroll
          for (int r = 0; r < 4; ++r)
            pw[(g * 16 + q * 4 + r) * 66 + bt * 16 + l15] = acc[g][bt][r];
    }
    __syncthreads();

    // ---- combine: thread owns (b=cb, m in [cmq,cmq+4)) ----
    {
      float4 hv = *(float4*)&hown[cb][cmq];
      u16x4 pk;
#pragma unroll
      for (int r = 0; r < 4; ++r) {
        int m = cmq + r;
        float hr = bh_lds[0][m], hz = bh_lds[1][m], hn = bh_lds[2][m];
#pragma unroll
        for (int ww = 0; ww < 4; ++ww) {
          const float* pp = (const float*)(const void*)h_stage[ww];
          hr += pp[( 0 + m) * 66 + cb];
          hz += pp[(16 + m) * 66 + cb];
          hn += pp[(32 + m) * 66 + cb];
        }
        float xr = bf2f(xq[0][r]), xz = bf2f(xq[1][r]), xn = bf2f(xq[2][r]);
        float rr = 1.f / (1.f + __expf(-(xr + hr)));
        float zz = 1.f / (1.f + __expf(-(xz + hz)));
        float ex = __expf(2.f * (xn + rr * hn));
        float nn = 1.f - 2.f / (ex + 1.f);       // tanh
        float hold = (r == 0) ? hv.x : (r == 1) ? hv.y : (r == 2) ? hv.z : hv.w;
        float hnew = (1.f - zz) * nn + zz * hold;
        if (r == 0) hv.x = hnew; else if (r == 1) hv.y = hnew; else if (r == 2) hv.z = hnew; else hv.w = hnew;
        pk[r] = f2bf(hnew);
      }
      *(float4*)&hown[cb][cmq] = hv;
      if (t + 1 < S_LEN) {
        // write-through 8B h store (sc0 sc1): never dirties L2
        __hip_atomic_store((unsigned long long*)(hnxt + (size_t)cb * HDIM + j0 + cmq),
                           __builtin_bit_cast(unsigned long long, pk),
                           __ATOMIC_RELAXED, __HIP_MEMORY_SCOPE_AGENT);
      }
    }
    __syncthreads();   // every wave drains vmcnt(0): ALL h stores at MALL

    if (t + 1 < S_LEN) {
      // arrive: own flag dword, no RMW, no contention, no wbl2
      if (tid == 0)
        __hip_atomic_store(&flags[p], (unsigned)(t + 1),
                           __ATOMIC_RELAXED, __HIP_MEMORY_SCOPE_AGENT);
      // prefetch xg for t+1 while waiting (latency hides under the poll)
#pragma unroll
      for (int g = 0; g < 3; ++g)
#pragma unroll
        for (int r = 0; r < 4; ++r)
          xq[g][r] = xg[((size_t)(t + 1) * GDIM + g * HDIM + j0 + cmq + r) * BATCH + cb];
      // wait: wave 0, lane i spins on flags[i] (coalesced 256B poll)
      if (tid < 64) {
        unsigned spins = 0;
        while (__hip_atomic_load(&flags[tid], __ATOMIC_RELAXED, __HIP_MEMORY_SCOPE_AGENT)
               < (unsigned)(t + 1)) {
          __builtin_amdgcn_s_sleep(1);
          if (++spins > 50000000u) break;  // safety: wrong answer beats a hang
        }
      }
      __syncthreads();
      // single buffer_inv sc1: fresh h for cached loads (L2-shared per XCD)
      __builtin_amdgcn_fence(__ATOMIC_ACQUIRE, "agent");
    }
  }

  // final h -> out[b][j]  (fp32, float4)
  *(float4*)(out + (size_t)cb * HDIM + j0 + cmq) = *(float4*)&hown[cb][cmq];
}

// ---------------------------------------------------------------------------
extern "C" void kernel_launch(void* const* d_in, const int* in_sizes, int n_in,
                              void* d_out, int out_size, void* d_ws, size_t ws_size,
                              hipStream_t stream) {
  const float* U   = (const float*)d_in[0];
  const float* Wih = (const float*)d_in[1];
  const float* Whh = (const float*)d_in[2];
  const float* bih = (const float*)d_in[3];
  const float* bhh = (const float*)d_in[4];
  float* out = (float*)d_out;

  char* ws = (char*)d_ws;
  const size_t XG_BYTES = (size_t)S_LEN * GDIM * BATCH * 2;  // 201326592
  unsigned short* xg   = (unsigned short*)ws;
  unsigned short* hbuf = (unsigned short*)(ws + XG_BYTES);
  const size_t H_BYTES = (size_t)2 * BATCH * HDIM * 2;       // 262144
  unsigned int* flags  = (unsigned int*)(ws + XG_BYTES + H_BYTES);

  // zero h(0) double-buffer + 64 flag dwords (ws is poisoned 0xAA each call)
  hipMemsetAsync(ws + XG_BYTES, 0, H_BYTES + 256, stream);

  hipLaunchKernelGGL(xg_gemm, dim3((32768 / 128) * (GDIM / 128)), dim3(256), 0, stream,
                     U, Wih, bih, xg);
  hipLaunchKernelGGL(gru_scan, dim3(64), dim3(256), 0, stream,
                     Whh, bhh, xg, hbuf, flags, out);
}

// Round 3
// 3483.265 us; speedup vs baseline: 1.3609x; 1.1808x over previous
//
#include <hip/hip_runtime.h>

// Problem constants (B,S,D,H = 64,512,1024,1024)
#define S_LEN 512
#define BATCH 64
#define HDIM  1024
#define GDIM  3072   // 3*H

typedef __attribute__((ext_vector_type(8))) short bf16x8;           // MFMA A/B frag (8 bf16)
typedef __attribute__((ext_vector_type(4))) float f32x4;            // MFMA C/D frag
typedef __attribute__((ext_vector_type(4))) unsigned short u16x4;   // 4 bf16

__device__ inline unsigned short f2bf(float f) {
  unsigned u = __builtin_bit_cast(unsigned, f);
  u += 0x7fffu + ((u >> 16) & 1u);          // RNE (inputs are normal floats)
  return (unsigned short)(u >> 16);
}
__device__ inline float bf2f(unsigned short h) {
  unsigned u = ((unsigned)h) << 16;
  return __builtin_bit_cast(float, u);
}
__device__ inline bf16x8 pack8(float4 a, float4 b) {
  bf16x8 r;
  r[0] = (short)f2bf(a.x); r[1] = (short)f2bf(a.y);
  r[2] = (short)f2bf(a.z); r[3] = (short)f2bf(a.w);
  r[4] = (short)f2bf(b.x); r[5] = (short)f2bf(b.y);
  r[6] = (short)f2bf(b.z); r[7] = (short)f2bf(b.w);
  return r;
}

// ---------------------------------------------------------------------------
// Phase 1: xg[s][g][b] = sum_d U[b][s][d] * Wih[g][d] + bih[g]   (bf16 out)
// (unchanged this round)
// ---------------------------------------------------------------------------
__global__ __launch_bounds__(256, 2) void xg_gemm(
    const float* __restrict__ U, const float* __restrict__ Wih,
    const float* __restrict__ bih, unsigned short* __restrict__ xg) {
  __shared__ bf16x8 Asub[512];   // 128 rows x 4 chunks (8KB)
  __shared__ bf16x8 Bsub[512];

  const int bid = blockIdx.x;
  const int nt = bid % 24;       // N-tile (gate cols) fastest: W_ih L2 reuse
  const int mt = bid / 24;
  const int tid = threadIdx.x;
  const int wave = tid >> 6, lane = tid & 63;
  const int q = lane >> 4, l15 = lane & 15;
  const int wm = wave >> 1, wn = wave & 1;

  const int srow = tid >> 1, shalf = tid & 1;
  const int arow = mt * 128 + srow;            // M index = s*64+b ordering
  const float* Ag = U + ((size_t)(arow & 63) * S_LEN + (arow >> 6)) * HDIM + shalf * 16;
  const float* Bg = Wih + (size_t)(nt * 128 + srow) * HDIM + shalf * 16;
  const int sw = (srow >> 1) & 3;
  const int slot0 = srow * 4 + ((shalf * 2) ^ sw);
  const int slot1 = srow * 4 + ((shalf * 2 + 1) ^ sw);

  f32x4 acc[4][4];
#pragma unroll
  for (int i = 0; i < 4; ++i)
#pragma unroll
    for (int j = 0; j < 4; ++j) acc[i][j] = (f32x4){0.f, 0.f, 0.f, 0.f};

  for (int kk = 0; kk < 32; ++kk) {
    const float4* ap = (const float4*)(Ag + kk * 32);
    float4 a0 = ap[0], a1 = ap[1], a2 = ap[2], a3 = ap[3];
    const float4* bp = (const float4*)(Bg + kk * 32);
    float4 b0 = bp[0], b1 = bp[1], b2 = bp[2], b3 = bp[3];
    Asub[slot0] = pack8(a0, a1);
    Asub[slot1] = pack8(a2, a3);
    Bsub[slot0] = pack8(b0, b1);
    Bsub[slot1] = pack8(b2, b3);
    __syncthreads();
    bf16x8 af[4], bfr[4];
#pragma unroll
    for (int i = 0; i < 4; ++i) {
      int ar = wm * 64 + i * 16 + l15;
      af[i] = Asub[ar * 4 + (q ^ ((ar >> 1) & 3))];
      int br = wn * 64 + i * 16 + l15;
      bfr[i] = Bsub[br * 4 + (q ^ ((br >> 1) & 3))];
    }
#pragma unroll
    for (int i = 0; i < 4; ++i)
#pragma unroll
      for (int j = 0; j < 4; ++j)
        acc[i][j] = __builtin_amdgcn_mfma_f32_16x16x32_bf16(af[i], bfr[j], acc[i][j], 0, 0, 0);
    __syncthreads();
  }

#pragma unroll
  for (int j = 0; j < 4; ++j) {
    int gcol = nt * 128 + wn * 64 + j * 16 + l15;
    float bias = bih[gcol];
#pragma unroll
    for (int i = 0; i < 4; ++i) {
      int rbase = mt * 128 + wm * 64 + i * 16 + q * 4;
      int s = rbase >> 6;
      int b0i = rbase & 63;
      u16x4 pk;
#pragma unroll
      for (int r = 0; r < 4; ++r) pk[r] = f2bf(acc[i][j][r] + bias);
      *(u16x4*)(xg + ((size_t)s * GDIM + gcol) * BATCH + b0i) = pk;
    }
  }
}

// ---------------------------------------------------------------------------
// Phase 2 (round-8): persistent GRU scan, 64 blocks x 512 threads.
//
// Round-7 crashed (GPU fault). Two candidates, both fixed here:
//   (a) sync arena grew past the known-safe 64 dwords -> possible ws OOB.
//       This round restores the EXACT round-5/6 footprint: XG + H + 256.
//   (b) batched load asm lacked early-clobber -> an output quad could alias a
//       later load's address pair. All asm outputs now "=&v".
//
// Protocol change vs round-6 (the actual optimization):
//   * DROP the per-step acquire fence (buffer_inv sc1). Round-6's step cost
//     was dominated by it: invalidating every XCD L2 forces h AND the xg
//     stream AND bias/weight lines to re-miss to MALL every step.
//   * h loads become direct-MALL reads: global_load_dwordx4 sc0 sc1
//     (bypass L1+L2, read fresh data at MALL). 16 concurrent loads per wave
//     (2 batches of 8, vmcnt-counted) -> one overlapped RT, reg-staged into
//     LDS with the G4 XOR swizzle (possible now that we control ds_write
//     addresses; the DMA path couldn't express sc1 or swizzle).
//   * h stores stay sc0sc1 8B atomics (write-through MALL, never dirty L2).
//   * flags: verbatim round-5/6 (64 dwords, store-own-flag + 64-lane poll).
//   * Everything else (xg, weights, bias) stays plainly cached -> L2 hot.
//
// LDS: 8 wave regions of [64 rows][128 shorts] (k-slice 128/wave), 16B chunk
// XOR-swizzled per G4: chunk' = (c&8) | ((c ^ row) & 7). MFMA ds_read_b128
// then distributes 64 lanes uniformly over banks (2-way = free). Per-wave
// partial buffer (3*16*66 f32 = 12.7KB) aliases the front of its own region
// after the MFMA phase (all reads data-feed the accs -> ordered), as in r6.
// ---------------------------------------------------------------------------
__global__ __launch_bounds__(512, 1) void gru_scan(
    const float* __restrict__ Whh, const float* __restrict__ bhh,
    const unsigned short* __restrict__ xg, unsigned short* __restrict__ hbuf,
    unsigned int* __restrict__ flags, float* __restrict__ out) {
  __shared__ unsigned short hls[8 * 8192];   // 128KB: 8 wave regions [64][128]
  __shared__ float bh_lds[3][16];

  const int p = blockIdx.x;
  const int j0 = p * 16;
  const int tid = threadIdx.x;
  const int w = tid >> 6, lane = tid & 63;
  const int q = lane >> 4, l15 = lane & 15;
  const int k0 = w * 128;            // wave's K-slice
  const int cb = tid >> 2;           // combine: batch row 0..63 (tid<256)
  const int cmq = (tid & 3) * 4;     // combine: m-quad 0,4,8,12

  // staging decomposition: lane covers row (lane>>4)+4j, chunk lane&15
  const int srow0 = lane >> 4;       // 0..3
  const int sc = lane & 15;          // 16B chunk 0..15 within k-slice

  // A-frags resident in VGPRs: wf[g][kk] = Whh[g*1024+j0+l15][k0+kk*32+q*8..]
  bf16x8 wf[3][4];
#pragma unroll
  for (int g = 0; g < 3; ++g) {
    const float* wrow = Whh + ((size_t)g * HDIM + j0 + l15) * HDIM + k0;
#pragma unroll
    for (int kk = 0; kk < 4; ++kk) {
      const float4* wp = (const float4*)(wrow + kk * 32 + q * 8);
      wf[g][kk] = pack8(wp[0], wp[1]);
    }
  }
  if (tid < 48) bh_lds[tid >> 4][tid & 15] = bhh[(tid >> 4) * HDIM + j0 + (tid & 15)];
  __syncthreads();

  // fp32 carry in registers (combine threads tid<256 own (b=cb, m=cmq..cmq+3))
  float4 hv = {0.f, 0.f, 0.f, 0.f};

  // prefetch xg for t=0
  unsigned short xq[3][4];
#pragma unroll
  for (int g = 0; g < 3; ++g)
#pragma unroll
    for (int r = 0; r < 4; ++r)
      xq[g][r] = xg[((size_t)g * HDIM + j0 + cmq + r) * BATCH + cb];

  const size_t HS = (size_t)BATCH * HDIM;

  for (int t = 0; t < S_LEN; ++t) {
    const unsigned short* hcur = hbuf + (size_t)(t & 1) * HS;
    unsigned short* hnxt = hbuf + (size_t)((t + 1) & 1) * HS;

    // ---- stage h[0:64][k0:k0+128) direct from MALL (sc0 sc1), 16 loads in
    //      flight, reg->LDS with G4 XOR swizzle ----
    {
      const unsigned short* gb = hcur + (size_t)srow0 * HDIM + k0 + sc * 8;
      const unsigned short *g0 = gb,            *g1 = gb + 4 * HDIM,
                           *g2 = gb + 8 * HDIM, *g3 = gb + 12 * HDIM,
                           *g4 = gb + 16 * HDIM,*g5 = gb + 20 * HDIM,
                           *g6 = gb + 24 * HDIM,*g7 = gb + 28 * HDIM;
      bf16x8 v0, v1, v2, v3, v4, v5, v6, v7;
      asm volatile(
          "global_load_dwordx4 %0, %8, off sc0 sc1\n\t"
          "global_load_dwordx4 %1, %9, off sc0 sc1\n\t"
          "global_load_dwordx4 %2, %10, off sc0 sc1\n\t"
          "global_load_dwordx4 %3, %11, off sc0 sc1\n\t"
          "global_load_dwordx4 %4, %12, off sc0 sc1\n\t"
          "global_load_dwordx4 %5, %13, off sc0 sc1\n\t"
          "global_load_dwordx4 %6, %14, off sc0 sc1\n\t"
          "global_load_dwordx4 %7, %15, off sc0 sc1"
          : "=&v"(v0), "=&v"(v1), "=&v"(v2), "=&v"(v3),
            "=&v"(v4), "=&v"(v5), "=&v"(v6), "=&v"(v7)
          : "v"(g0), "v"(g1), "v"(g2), "v"(g3),
            "v"(g4), "v"(g5), "v"(g6), "v"(g7));
      const unsigned short *g8 = gb + 32 * HDIM, *g9 = gb + 36 * HDIM,
                           *gA = gb + 40 * HDIM, *gB = gb + 44 * HDIM,
                           *gC = gb + 48 * HDIM, *gD = gb + 52 * HDIM,
                           *gE = gb + 56 * HDIM, *gF = gb + 60 * HDIM;
      bf16x8 v8, v9, vA, vB, vC, vD, vE, vF;
      asm volatile(
          "global_load_dwordx4 %0, %8, off sc0 sc1\n\t"
          "global_load_dwordx4 %1, %9, off sc0 sc1\n\t"
          "global_load_dwordx4 %2, %10, off sc0 sc1\n\t"
          "global_load_dwordx4 %3, %11, off sc0 sc1\n\t"
          "global_load_dwordx4 %4, %12, off sc0 sc1\n\t"
          "global_load_dwordx4 %5, %13, off sc0 sc1\n\t"
          "global_load_dwordx4 %6, %14, off sc0 sc1\n\t"
          "global_load_dwordx4 %7, %15, off sc0 sc1"
          : "=&v"(v8), "=&v"(v9), "=&v"(vA), "=&v"(vB),
            "=&v"(vC), "=&v"(vD), "=&v"(vE), "=&v"(vF)
          : "v"(g8), "v"(g9), "v"(gA), "v"(gB),
            "v"(gC), "v"(gD), "v"(gE), "v"(gF));

#define STW(J, VV)                                                        \
      {                                                                   \
        const int row_ = srow0 + 4 * (J);                                 \
        const int c2_ = (sc & 8) | ((sc ^ row_) & 7);                     \
        *(bf16x8*)&hls[w * 8192 + row_ * 128 + c2_ * 8] = (VV);           \
      }
      asm volatile("s_waitcnt vmcnt(8)" ::: "memory");
      __builtin_amdgcn_sched_barrier(0);
      STW(0, v0) STW(1, v1) STW(2, v2) STW(3, v3)
      STW(4, v4) STW(5, v5) STW(6, v6) STW(7, v7)
      asm volatile("s_waitcnt vmcnt(0)" ::: "memory");
      __builtin_amdgcn_sched_barrier(0);
      STW(8, v8) STW(9, v9) STW(10, vA) STW(11, vB)
      STW(12, vC) STW(13, vD) STW(14, vE) STW(15, vF)
#undef STW
    }

    // ---- GEMM phase: wave-private region, swizzled conflict-free reads ----
    f32x4 acc[3][4];
#pragma unroll
    for (int g = 0; g < 3; ++g)
#pragma unroll
      for (int bt = 0; bt < 4; ++bt) acc[g][bt] = (f32x4){0.f, 0.f, 0.f, 0.f};

#pragma unroll
    for (int kk = 0; kk < 4; ++kk) {
      const int c = kk * 4 + q;
      bf16x8 hB[4];
#pragma unroll
      for (int bt = 0; bt < 4; ++bt) {
        const int row = bt * 16 + l15;
        const int c2 = (c & 8) | ((c ^ row) & 7);
        hB[bt] = *(const bf16x8*)&hls[w * 8192 + row * 128 + c2 * 8];
      }
#pragma unroll
      for (int g = 0; g < 3; ++g) {
        acc[g][0] = __builtin_amdgcn_mfma_f32_16x16x32_bf16(wf[g][kk], hB[0], acc[g][0], 0, 0, 0);
        acc[g][1] = __builtin_amdgcn_mfma_f32_16x16x32_bf16(wf[g][kk], hB[1], acc[g][1], 0, 0, 0);
        acc[g][2] = __builtin_amdgcn_mfma_f32_16x16x32_bf16(wf[g][kk], hB[2], acc[g][2], 0, 0, 0);
        acc[g][3] = __builtin_amdgcn_mfma_f32_16x16x32_bf16(wf[g][kk], hB[3], acc[g][3], 0, 0, 0);
      }
    }
    __builtin_amdgcn_sched_barrier(0);

    // partials aliased into wave w's own region (all region reads feed accs):
    // layout float[(g*16 + m)*66 + b], m = q*4+r, b = bt*16+l15
    {
      float* pw = (float*)&hls[w * 8192];
      asm volatile("" : "+v"(pw));   // opaque: may alias anything
#pragma unroll
      for (int g = 0; g < 3; ++g)
#pragma unroll
        for (int bt = 0; bt < 4; ++bt)
#pragma unroll
          for (int r = 0; r < 4; ++r)
            pw[(g * 16 + q * 4 + r) * 66 + bt * 16 + l15] = acc[g][bt][r];
    }
    __syncthreads();

    // ---- combine: thread owns (b=cb, m in [cmq,cmq+4)) ----
    if (tid < 256) {
      u16x4 pk;
#pragma unroll
      for (int r = 0; r < 4; ++r) {
        int m = cmq + r;
        float hr = bh_lds[0][m], hz = bh_lds[1][m], hn = bh_lds[2][m];
#pragma unroll
        for (int ww = 0; ww < 8; ++ww) {
          const float* pp = (const float*)&hls[ww * 8192];
          hr += pp[( 0 + m) * 66 + cb];
          hz += pp[(16 + m) * 66 + cb];
          hn += pp[(32 + m) * 66 + cb];
        }
        float xr = bf2f(xq[0][r]), xz = bf2f(xq[1][r]), xn = bf2f(xq[2][r]);
        float rr = 1.f / (1.f + __expf(-(xr + hr)));
        float zz = 1.f / (1.f + __expf(-(xz + hz)));
        float ex = __expf(2.f * (xn + rr * hn));
        float nn = 1.f - 2.f / (ex + 1.f);       // tanh
        float hold = (r == 0) ? hv.x : (r == 1) ? hv.y : (r == 2) ? hv.z : hv.w;
        float hnew = (1.f - zz) * nn + zz * hold;
        if (r == 0) hv.x = hnew; else if (r == 1) hv.y = hnew; else if (r == 2) hv.z = hnew; else hv.w = hnew;
        pk[r] = f2bf(hnew);
      }
      if (t + 1 < S_LEN) {
        // write-through 8B h store (sc0 sc1): never dirties L2
        __hip_atomic_store((unsigned long long*)(hnxt + (size_t)cb * HDIM + j0 + cmq),
                           __builtin_bit_cast(unsigned long long, pk),
                           __ATOMIC_RELAXED, __HIP_MEMORY_SCOPE_AGENT);
      }
    }
    __syncthreads();   // every wave drains vmcnt(0): ALL h stores at MALL

    if (t + 1 < S_LEN) {
      // arrive: own flag dword, no RMW, no contention, no wbl2
      if (tid == 0)
        __hip_atomic_store(&flags[p], (unsigned)(t + 1),
                           __ATOMIC_RELAXED, __HIP_MEMORY_SCOPE_AGENT);
      // prefetch xg for t+1 while waiting (latency hides under the poll)
#pragma unroll
      for (int g = 0; g < 3; ++g)
#pragma unroll
        for (int r = 0; r < 4; ++r)
          xq[g][r] = xg[((size_t)(t + 1) * GDIM + g * HDIM + j0 + cmq + r) * BATCH + cb];
      // wait: wave 0, lane i spins on flags[i] (coalesced 256B poll)
      if (tid < 64) {
        unsigned spins = 0;
        while (__hip_atomic_load(&flags[tid], __ATOMIC_RELAXED, __HIP_MEMORY_SCOPE_AGENT)
               < (unsigned)(t + 1)) {
          __builtin_amdgcn_s_sleep(1);
          if (++spins > 50000000u) break;  // safety: wrong answer beats a hang
        }
      }
      __syncthreads();
      // NO acquire fence / buffer_inv: all cross-block data moves via sc0sc1
      // ops (h loads+stores, flag atomics). L2 keeps xg/weights/bias hot.
    }
  }

  // final h -> out[b][j]  (fp32, float4)
  if (tid < 256)
    *(float4*)(out + (size_t)cb * HDIM + j0 + cmq) = hv;
}

// ---------------------------------------------------------------------------
extern "C" void kernel_launch(void* const* d_in, const int* in_sizes, int n_in,
                              void* d_out, int out_size, void* d_ws, size_t ws_size,
                              hipStream_t stream) {
  const float* U   = (const float*)d_in[0];
  const float* Wih = (const float*)d_in[1];
  const float* Whh = (const float*)d_in[2];
  const float* bih = (const float*)d_in[3];
  const float* bhh = (const float*)d_in[4];
  float* out = (float*)d_out;

  char* ws = (char*)d_ws;
  const size_t XG_BYTES = (size_t)S_LEN * GDIM * BATCH * 2;  // 201326592
  unsigned short* xg   = (unsigned short*)ws;
  unsigned short* hbuf = (unsigned short*)(ws + XG_BYTES);
  const size_t H_BYTES = (size_t)2 * BATCH * HDIM * 2;       // 262144
  unsigned int* flags  = (unsigned int*)(ws + XG_BYTES + H_BYTES);

  // zero h(0) double-buffer + 64 flag dwords (ws is poisoned 0xAA each call)
  // footprint: XG + H + 256 exactly — the known-safe budget.
  hipMemsetAsync(ws + XG_BYTES, 0, H_BYTES + 256, stream);

  hipLaunchKernelGGL(xg_gemm, dim3((32768 / 128) * (GDIM / 128)), dim3(256), 0, stream,
                     U, Wih, bih, xg);
  hipLaunchKernelGGL(gru_scan, dim3(64), dim3(512), 0, stream,
                     Whh, bhh, xg, hbuf, flags, out);
}